// Round 9
// baseline (99.062 us; speedup 1.0000x reference)
//
#include <hip/hip_runtime.h>

#define GDIM 38
#define GG   (GDIM * GDIM)          // 1444
#define TOTAL (GDIM * GDIM * GDIM)  // 54872
#define NPARTB 128                  // private per-block histogram partials

typedef float f32x4 __attribute__((ext_vector_type(4)));

// 13 half-shell displacements (buckets_per_cutoff == 1), matches VEC_DISP
__device__ __constant__ int c_disp[13][3] = {
    {-1, 0, 0}, {-1, -1, 0}, {0, -1, 0}, {1, -1, 0},
    {-1, 1, -1}, {0, 1, -1}, {1, 1, -1}, {-1, 0, -1},
    {0, 0, -1}, {1, 0, -1}, {-1, -1, -1}, {0, -1, -1}, {1, -1, -1}};

// translation-case LUT indexed by cx*9+cy*3+cz, cat: 0=low(0), 1=mid, 2=high(G+1)
__device__ __constant__ unsigned char c_case[27] = {
    11,  2, 0,   8,  1, 0,   5, 14, 0,
    12,  3, 0,   9,  0, 0,   6, 15, 0,
    13,  4, 0,  10, 17, 0,   7, 16, 0};

#define BS 256
// LDS f32x4 layout: [0,192)=frac/coords, [192,1024)=nf, [1024,1856)=nc
#define F4_FRAC 0
#define F4_NF   192
#define F4_NC   1024

// A: pure streaming kernel — no atomics at all
__global__ __launch_bounds__(BS) void cell_atoms_kernel(
    const float* __restrict__ coords, const float* __restrict__ cell,
    float* __restrict__ out, int N)
{
    __shared__ f32x4 s4[1856];               // 29.7 KB
    float* s = (float*)s4;

    const int tid = threadIdx.x;
    const long long blockbase = (long long)blockIdx.x * BS;
    const int valid = (int)min((long long)BS, (long long)N - blockbase);
    const bool full = (valid == BS);
    const bool i_ok = tid < valid;

    const long long OFF0 = 0;            // frac       (3N)
    const long long OFF1 = 3LL * N;      // flat index (N)
    const long long OFF2 = 4LL * N;      // neigh flat (13N)
    const long long OFF3 = 17LL * N;     // neigh case (13N)

    // ---- coalesced coord load into LDS ----
    if (full) {
        const f32x4* src = (const f32x4*)(coords + blockbase * 3);
        if (tid < 192) s4[F4_FRAC + tid] = src[tid];
    } else {
        const float* src = coords + blockbase * 3;
        for (int j = tid; j < valid * 3; j += BS) s[j] = src[j];
    }
    __syncthreads();

    // ---- per-atom compute; frac overwrites own coords in place ----
    int v[3];
    if (i_ok) {
#pragma unroll
        for (int a = 0; a < 3; ++a) {
            float d = cell[4 * a];              // diagonal
            float f = s[3 * tid + a] / d;       // IEEE divide, matches jnp
            f = f - floorf(f);
            if (f >= 1.0f) f -= 1.0f;
            if (f < 0.0f)  f += 1.0f;
            s[3 * tid + a] = f;
            v[a] = (int)floorf(f * (float)GDIM);
        }

        // flat index (coalesced direct nt store)
        int flat = v[0] * GG + v[1] * GDIM + v[2];
        __builtin_nontemporal_store((float)flat, &out[OFF1 + blockbase + tid]);

        // neighbor flat + case → staged into LDS
#pragma unroll
        for (int k = 0; k < 13; ++k) {
            int cidx = 0, f2 = 0;
#pragma unroll
            for (int a = 0; a < 3; ++a) {
                int n = v[a] + 1 + c_disp[k][a];   // padded coord, [0, G+1]
                int cat = (n == 0) ? 0 : ((n == GDIM + 1) ? 2 : 1);
                int m = (n == 0) ? (GDIM - 1) : ((n == GDIM + 1) ? 0 : n - 1);
                cidx = cidx * 3 + cat;
                f2 += m * (a == 0 ? GG : (a == 1 ? GDIM : 1));
            }
            s[4 * F4_NF + 13 * tid + k] = (float)f2;           // stride 13: 2-way = free
            s[4 * F4_NC + 13 * tid + k] = (float)c_case[cidx];
        }
    }
    __syncthreads();

    // ---- single drain: frac, nf, nc as nontemporal f32x4 ----
    if (full) {
        f32x4* dfrac = (f32x4*)(out + OFF0 + blockbase * 3);
        if (tid < 192) __builtin_nontemporal_store(s4[F4_FRAC + tid], &dfrac[tid]);

        f32x4* dnf = (f32x4*)(out + OFF2 + blockbase * 13);
        f32x4* dnc = (f32x4*)(out + OFF3 + blockbase * 13);
#pragma unroll
        for (int j = tid; j < 832; j += BS) {
            __builtin_nontemporal_store(s4[F4_NF + j], &dnf[j]);
            __builtin_nontemporal_store(s4[F4_NC + j], &dnc[j]);
        }
    } else {
        float* dfrac = out + OFF0 + blockbase * 3;
        for (int j = tid; j < valid * 3; j += BS)
            __builtin_nontemporal_store(s[j], &dfrac[j]);
        float* dnf = out + OFF2 + blockbase * 13;
        float* dnc = out + OFF3 + blockbase * 13;
        for (int j = tid; j < valid * 13; j += BS) {
            __builtin_nontemporal_store(s[4 * F4_NF + j], &dnf[j]);
            __builtin_nontemporal_store(s[4 * F4_NC + j], &dnc[j]);
        }
    }
}

// B: histogram from stored flat[], private partial per block, workgroup-scope
// atomics (XCD-L2 local — no cross-XCD coherence traffic)
__global__ __launch_bounds__(1024) void hist_kernel(
    const float* __restrict__ flatf, int* __restrict__ parts, int N)
{
    int* mine = parts + (long long)blockIdx.x * TOTAL;

    // zero private region (L2-resident)
    int4* m4 = (int4*)mine;
    for (int j = threadIdx.x; j < TOTAL / 4; j += 1024)
        m4[j] = make_int4(0, 0, 0, 0);
    __syncthreads();

    const long long stride = (long long)NPARTB * 1024;
    for (long long i = (long long)blockIdx.x * 1024 + threadIdx.x; i < N; i += stride) {
        int flat = (int)flatf[i];
        __hip_atomic_fetch_add(&mine[flat], 1, __ATOMIC_RELAXED,
                               __HIP_MEMORY_SCOPE_WORKGROUP);
    }
}

// C: collapse NPARTB partials into cnt
__global__ __launch_bounds__(256) void reduce_kernel(
    const int* __restrict__ parts, int* __restrict__ cnt_out)
{
    int idx = blockIdx.x * 256 + threadIdx.x;
    if (idx >= TOTAL) return;
    int sum = 0;
#pragma unroll 8
    for (int p = 0; p < NPARTB; ++p) sum += parts[(long long)p * TOTAL + idx];
    cnt_out[idx] = sum;
}

// D: parallel scan — 54 blocks; each sums everything before its range
__global__ __launch_bounds__(1024) void scan_kernel(
    const int* __restrict__ cnt,
    float* __restrict__ out_count,
    float* __restrict__ out_cum)
{
    __shared__ int lds[1024];
    const int t = threadIdx.x;
    const int base = blockIdx.x * 1024;

    int pre = 0;
    for (int j = t; j < base; j += 1024) pre += cnt[j];
    lds[t] = pre;
    __syncthreads();
    for (int off = 512; off > 0; off >>= 1) {
        if (t < off) lds[t] += lds[t + off];
        __syncthreads();
    }
    const int blockpre = lds[0];
    __syncthreads();

    const int idx = base + t;
    const int c = (idx < TOTAL) ? cnt[idx] : 0;

    lds[t] = c;
    __syncthreads();
    for (int off = 1; off < 1024; off <<= 1) {
        int vprev = (t >= off) ? lds[t - off] : 0;
        __syncthreads();
        lds[t] += vprev;
        __syncthreads();
    }
    const int exc = lds[t] - c;

    if (idx < TOTAL) {
        __builtin_nontemporal_store((float)c, &out_count[idx]);
        __builtin_nontemporal_store((float)(blockpre + exc), &out_cum[idx]);
    }
}

extern "C" void kernel_launch(void* const* d_in, const int* in_sizes, int n_in,
                              void* d_out, int out_size, void* d_ws, size_t ws_size,
                              hipStream_t stream)
{
    const float* coords = (const float*)d_in[0];
    const float* cell   = (const float*)d_in[1];
    float* out = (float*)d_out;
    int* parts = (int*)d_ws;                       // NPARTB * TOTAL ints (28 MB)
    int* cnt   = parts + (long long)NPARTB * TOTAL;

    // out_size = 30N + 2*TOTAL
    int N = (int)((out_size - 2 * TOTAL) / 30);

    cell_atoms_kernel<<<(N + BS - 1) / BS, BS, 0, stream>>>(coords, cell, out, N);

    hist_kernel<<<NPARTB, 1024, 0, stream>>>(out + 3LL * N, parts, N);

    reduce_kernel<<<(TOTAL + 255) / 256, 256, 0, stream>>>(parts, cnt);

    long long off4 = 30LL * N;  // count then cumcount at the tail
    scan_kernel<<<(TOTAL + 1023) / 1024, 1024, 0, stream>>>(
        cnt, out + off4, out + off4 + TOTAL);
}

// Round 10
// 63.067 us; speedup vs baseline: 1.5707x; 1.5707x over previous
//
#include <hip/hip_runtime.h>

#define GDIM 38
#define GG   (GDIM * GDIM)          // 1444
#define TOTAL (GDIM * GDIM * GDIM)  // 54872
#define HALF  (TOTAL / 2)           // 27436 buckets per half
#define HWORDS (HALF / 2)           // 13718 packed u32 words per half
#define NSLICE 128                  // atom slices for histogram

typedef float f32x4 __attribute__((ext_vector_type(4)));

// 13 half-shell displacements (buckets_per_cutoff == 1), matches VEC_DISP
__device__ __constant__ int c_disp[13][3] = {
    {-1, 0, 0}, {-1, -1, 0}, {0, -1, 0}, {1, -1, 0},
    {-1, 1, -1}, {0, 1, -1}, {1, 1, -1}, {-1, 0, -1},
    {0, 0, -1}, {1, 0, -1}, {-1, -1, -1}, {0, -1, -1}, {1, -1, -1}};

// translation-case LUT indexed by cx*9+cy*3+cz, cat: 0=low(0), 1=mid, 2=high(G+1)
__device__ __constant__ unsigned char c_case[27] = {
    11,  2, 0,   8,  1, 0,   5, 14, 0,
    12,  3, 0,   9,  0, 0,   6, 15, 0,
    13,  4, 0,  10, 17, 0,   7, 16, 0};

#define BS 256
// LDS f32x4 layout: [0,192)=frac/coords, [192,1024)=nf, [1024,1856)=nc
#define F4_FRAC 0
#define F4_NF   192
#define F4_NC   1024

// A: pure streaming kernel — no atomics
__global__ __launch_bounds__(BS) void cell_atoms_kernel(
    const float* __restrict__ coords, const float* __restrict__ cell,
    float* __restrict__ out, int N)
{
    __shared__ f32x4 s4[1856];               // 29.7 KB
    float* s = (float*)s4;

    const int tid = threadIdx.x;
    const long long blockbase = (long long)blockIdx.x * BS;
    const int valid = (int)min((long long)BS, (long long)N - blockbase);
    const bool full = (valid == BS);
    const bool i_ok = tid < valid;

    const long long OFF0 = 0;            // frac       (3N)
    const long long OFF1 = 3LL * N;      // flat index (N)
    const long long OFF2 = 4LL * N;      // neigh flat (13N)
    const long long OFF3 = 17LL * N;     // neigh case (13N)

    // ---- coalesced coord load into LDS ----
    if (full) {
        const f32x4* src = (const f32x4*)(coords + blockbase * 3);
        if (tid < 192) s4[F4_FRAC + tid] = src[tid];
    } else {
        const float* src = coords + blockbase * 3;
        for (int j = tid; j < valid * 3; j += BS) s[j] = src[j];
    }
    __syncthreads();

    // ---- per-atom compute; frac overwrites own coords in place ----
    int v[3];
    if (i_ok) {
#pragma unroll
        for (int a = 0; a < 3; ++a) {
            float d = cell[4 * a];              // diagonal
            float f = s[3 * tid + a] / d;       // IEEE divide, matches jnp
            f = f - floorf(f);
            if (f >= 1.0f) f -= 1.0f;
            if (f < 0.0f)  f += 1.0f;
            s[3 * tid + a] = f;
            v[a] = (int)floorf(f * (float)GDIM);
        }

        int flat = v[0] * GG + v[1] * GDIM + v[2];
        __builtin_nontemporal_store((float)flat, &out[OFF1 + blockbase + tid]);

#pragma unroll
        for (int k = 0; k < 13; ++k) {
            int cidx = 0, f2 = 0;
#pragma unroll
            for (int a = 0; a < 3; ++a) {
                int n = v[a] + 1 + c_disp[k][a];   // padded coord, [0, G+1]
                int cat = (n == 0) ? 0 : ((n == GDIM + 1) ? 2 : 1);
                int m = (n == 0) ? (GDIM - 1) : ((n == GDIM + 1) ? 0 : n - 1);
                cidx = cidx * 3 + cat;
                f2 += m * (a == 0 ? GG : (a == 1 ? GDIM : 1));
            }
            s[4 * F4_NF + 13 * tid + k] = (float)f2;           // stride 13: 2-way = free
            s[4 * F4_NC + 13 * tid + k] = (float)c_case[cidx];
        }
    }
    __syncthreads();

    // ---- single drain: frac, nf, nc as nontemporal f32x4 ----
    if (full) {
        f32x4* dfrac = (f32x4*)(out + OFF0 + blockbase * 3);
        if (tid < 192) __builtin_nontemporal_store(s4[F4_FRAC + tid], &dfrac[tid]);

        f32x4* dnf = (f32x4*)(out + OFF2 + blockbase * 13);
        f32x4* dnc = (f32x4*)(out + OFF3 + blockbase * 13);
#pragma unroll
        for (int j = tid; j < 832; j += BS) {
            __builtin_nontemporal_store(s4[F4_NF + j], &dnf[j]);
            __builtin_nontemporal_store(s4[F4_NC + j], &dnc[j]);
        }
    } else {
        float* dfrac = out + OFF0 + blockbase * 3;
        for (int j = tid; j < valid * 3; j += BS)
            __builtin_nontemporal_store(s[j], &dfrac[j]);
        float* dnf = out + OFF2 + blockbase * 13;
        float* dnc = out + OFF3 + blockbase * 13;
        for (int j = tid; j < valid * 13; j += BS) {
            __builtin_nontemporal_store(s[4 * F4_NF + j], &dnf[j]);
            __builtin_nontemporal_store(s[4 * F4_NC + j], &dnc[j]);
        }
    }
}

// B: LDS-packed-u16 histogram. 256 blocks = (slice s = b>>1) x (half h = b&1).
// Each block: zero 55KB LDS, coalesced-read its atom slice, LDS-atomic the
// flats in its bucket-half, flush packed partial coalesced. No global RMW.
__global__ __launch_bounds__(1024) void hist_kernel(
    const float* __restrict__ flatf, unsigned int* __restrict__ parts, int N)
{
    __shared__ unsigned int h[HWORDS];       // 54.9 KB
    const int t = threadIdx.x;
    const int half = blockIdx.x & 1;         // bucket half
    const int slice = blockIdx.x >> 1;       // atom slice
    const int lo = half * HALF;              // bucket range [lo, lo+HALF)

    for (int j = t; j < HWORDS; j += 1024) h[j] = 0u;
    __syncthreads();

    for (long long i = (long long)slice * 1024 + t; i < N;
         i += (long long)NSLICE * 1024) {
        int flat = (int)flatf[i] - lo;
        if ((unsigned)flat < (unsigned)HALF)
            atomicAdd(&h[flat >> 1], 1u << ((flat & 1) * 16));
    }
    __syncthreads();

    unsigned int* dst = parts + (long long)blockIdx.x * HWORDS;
    for (int j = t; j < HWORDS; j += 1024)
        __builtin_nontemporal_store(h[j], &dst[j]);
}

// C: collapse 128 slices per (half, word), unpack u16 pairs -> cnt + count out
__global__ __launch_bounds__(256) void reduce_kernel(
    const unsigned int* __restrict__ parts, int* __restrict__ cnt,
    float* __restrict__ out_count)
{
    int j = blockIdx.x * 256 + threadIdx.x;  // word index in [0, HWORDS)
    if (j >= HWORDS) return;
#pragma unroll
    for (int half = 0; half < 2; ++half) {
        unsigned int sum = 0;
        for (int s = 0; s < NSLICE; ++s)
            sum += parts[(long long)(2 * s + half) * HWORDS + j];
        int b = half * HALF + 2 * j;
        int c0 = (int)(sum & 0xFFFFu), c1 = (int)(sum >> 16);
        cnt[b]     = c0;
        cnt[b + 1] = c1;
        out_count[b]     = (float)c0;
        out_count[b + 1] = (float)c1;
    }
}

// D: parallel scan — 54 blocks; each sums everything before its range
__global__ __launch_bounds__(1024) void scan_kernel(
    const int* __restrict__ cnt, float* __restrict__ out_cum)
{
    __shared__ int lds[1024];
    const int t = threadIdx.x;
    const int base = blockIdx.x * 1024;

    int pre = 0;
    for (int j = t; j < base; j += 1024) pre += cnt[j];
    lds[t] = pre;
    __syncthreads();
    for (int off = 512; off > 0; off >>= 1) {
        if (t < off) lds[t] += lds[t + off];
        __syncthreads();
    }
    const int blockpre = lds[0];
    __syncthreads();

    const int idx = base + t;
    const int c = (idx < TOTAL) ? cnt[idx] : 0;

    lds[t] = c;
    __syncthreads();
    for (int off = 1; off < 1024; off <<= 1) {
        int vprev = (t >= off) ? lds[t - off] : 0;
        __syncthreads();
        lds[t] += vprev;
        __syncthreads();
    }
    const int exc = lds[t] - c;

    if (idx < TOTAL)
        __builtin_nontemporal_store((float)(blockpre + exc), &out_cum[idx]);
}

extern "C" void kernel_launch(void* const* d_in, const int* in_sizes, int n_in,
                              void* d_out, int out_size, void* d_ws, size_t ws_size,
                              hipStream_t stream)
{
    const float* coords = (const float*)d_in[0];
    const float* cell   = (const float*)d_in[1];
    float* out = (float*)d_out;
    unsigned int* parts = (unsigned int*)d_ws;           // 256*HWORDS u32 = 14MB
    int* cnt = (int*)(parts + 256LL * HWORDS);

    // out_size = 30N + 2*TOTAL
    int N = (int)((out_size - 2 * TOTAL) / 30);

    cell_atoms_kernel<<<(N + BS - 1) / BS, BS, 0, stream>>>(coords, cell, out, N);

    long long off4 = 30LL * N;  // count then cumcount at the tail
    hist_kernel<<<2 * NSLICE, 1024, 0, stream>>>(out + 3LL * N, parts, N);
    reduce_kernel<<<(HWORDS + 255) / 256, 256, 0, stream>>>(parts, cnt, out + off4);
    scan_kernel<<<(TOTAL + 1023) / 1024, 1024, 0, stream>>>(cnt, out + off4 + TOTAL);
}

// Round 11
// 60.050 us; speedup vs baseline: 1.6496x; 1.0502x over previous
//
#include <hip/hip_runtime.h>

#define GDIM 38
#define GG   (GDIM * GDIM)          // 1444
#define TOTAL (GDIM * GDIM * GDIM)  // 54872
#define HALF  (TOTAL / 2)           // 27436 buckets per half
#define HWORDS (HALF / 2)           // 13718 packed u32 words per half
#define NSLICE 64                   // atom slices for histogram

typedef float f32x4 __attribute__((ext_vector_type(4)));

// 13 half-shell displacements (buckets_per_cutoff == 1), matches VEC_DISP
__device__ __constant__ int c_disp[13][3] = {
    {-1, 0, 0}, {-1, -1, 0}, {0, -1, 0}, {1, -1, 0},
    {-1, 1, -1}, {0, 1, -1}, {1, 1, -1}, {-1, 0, -1},
    {0, 0, -1}, {1, 0, -1}, {-1, -1, -1}, {0, -1, -1}, {1, -1, -1}};

// translation-case LUT indexed by cx*9+cy*3+cz, cat: 0=low(0), 1=mid, 2=high(G+1)
__device__ __constant__ unsigned char c_case[27] = {
    11,  2, 0,   8,  1, 0,   5, 14, 0,
    12,  3, 0,   9,  0, 0,   6, 15, 0,
    13,  4, 0,  10, 17, 0,   7, 16, 0};

#define BS 256

// A: barrier-free streaming kernel — all LDS staging is WAVE-PRIVATE, so no
// __syncthreads anywhere; waves' load/compute/drain phases interleave freely.
__global__ __launch_bounds__(BS) void cell_atoms_kernel(
    const float* __restrict__ coords, const float* __restrict__ cell,
    float* __restrict__ out, int N)
{
    __shared__ float s[7424];               // 29.7 KB: 4 waves × (192+832+832)
    const int tid  = threadIdx.x;
    const int w    = tid >> 6;
    const int lane = tid & 63;
    const long long wbase = (long long)blockIdx.x * BS + 64 * w;
    if (wbase >= N) return;

    float* sc  = s + 192 * w;               // coords→frac in place
    float* snf = s + 768 + 832 * w;         // neighbor flat
    float* snc = s + 4096 + 832 * w;        // neighbor case

    const long long OFF1 = 3LL * N;
    const long long OFF2 = 4LL * N;
    const long long OFF3 = 17LL * N;

    const bool fullwave = (wbase + 64 <= N);
    const int nval = fullwave ? 64 : (int)(N - wbase);

    // ---- stage this wave's coords (coalesced f32x4; same-wave ⇒ lgkmcnt only)
    if (fullwave) {
        const f32x4* src = (const f32x4*)(coords + wbase * 3);
        if (lane < 48) ((f32x4*)sc)[lane] = src[lane];
    } else {
        const float* src = coords + wbase * 3;
        for (int j = lane; j < nval * 3; j += 64) sc[j] = src[j];
    }

    if (lane < nval) {
        int v[3];
#pragma unroll
        for (int a = 0; a < 3; ++a) {
            float d = cell[4 * a];              // diagonal
            float f = sc[3 * lane + a] / d;     // IEEE divide, matches jnp
            f = f - floorf(f);
            if (f >= 1.0f) f -= 1.0f;
            if (f < 0.0f)  f += 1.0f;
            sc[3 * lane + a] = f;               // frac overwrites coord in place
            v[a] = (int)floorf(f * (float)GDIM);
        }

        int flat = v[0] * GG + v[1] * GDIM + v[2];
        __builtin_nontemporal_store((float)flat, &out[OFF1 + wbase + lane]);

#pragma unroll
        for (int k = 0; k < 13; ++k) {
            int cidx = 0, f2 = 0;
#pragma unroll
            for (int a = 0; a < 3; ++a) {
                int n = v[a] + 1 + c_disp[k][a];   // padded coord, [0, G+1]
                int cat = (n == 0) ? 0 : ((n == GDIM + 1) ? 2 : 1);
                int m = (n == 0) ? (GDIM - 1) : ((n == GDIM + 1) ? 0 : n - 1);
                cidx = cidx * 3 + cat;
                f2 += m * (a == 0 ? GG : (a == 1 ? GDIM : 1));
            }
            snf[13 * lane + k] = (float)f2;        // stride 13: 2-way = free
            snc[13 * lane + k] = (float)c_case[cidx];
        }
    }

    // ---- drain this wave's segments (coalesced nt f32x4; same-wave RAW via lgkmcnt)
    if (fullwave) {
        f32x4* dfr = (f32x4*)(out + wbase * 3);
        if (lane < 48) __builtin_nontemporal_store(((f32x4*)sc)[lane], &dfr[lane]);

        f32x4* dnf = (f32x4*)(out + OFF2 + wbase * 13);
        f32x4* dnc = (f32x4*)(out + OFF3 + wbase * 13);
#pragma unroll
        for (int j = lane; j < 208; j += 64) {
            __builtin_nontemporal_store(((f32x4*)snf)[j], &dnf[j]);
            __builtin_nontemporal_store(((f32x4*)snc)[j], &dnc[j]);
        }
    } else {
        float* dfr = out + wbase * 3;
        for (int j = lane; j < nval * 3; j += 64)
            __builtin_nontemporal_store(sc[j], &dfr[j]);
        float* dnf = out + OFF2 + wbase * 13;
        float* dnc = out + OFF3 + wbase * 13;
        for (int j = lane; j < nval * 13; j += 64) {
            __builtin_nontemporal_store(snf[j], &dnf[j]);
            __builtin_nontemporal_store(snc[j], &dnc[j]);
        }
    }
}

// B: LDS-packed-u16 histogram. 128 blocks = (slice s = b>>1) x (half h = b&1).
__global__ __launch_bounds__(1024) void hist_kernel(
    const float* __restrict__ flatf, unsigned int* __restrict__ parts, int N)
{
    __shared__ unsigned int h[HWORDS];       // 54.9 KB
    const int t = threadIdx.x;
    const int half = blockIdx.x & 1;         // bucket half
    const int slice = blockIdx.x >> 1;       // atom slice
    const int lo = half * HALF;              // bucket range [lo, lo+HALF)

    for (int j = t; j < HWORDS; j += 1024) h[j] = 0u;
    __syncthreads();

    for (long long i = (long long)slice * 1024 + t; i < N;
         i += (long long)NSLICE * 1024) {
        int flat = (int)flatf[i] - lo;
        if ((unsigned)flat < (unsigned)HALF)
            atomicAdd(&h[flat >> 1], 1u << ((flat & 1) * 16));
    }
    __syncthreads();

    unsigned int* dst = parts + (long long)blockIdx.x * HWORDS;
    for (int j = t; j < HWORDS; j += 1024)
        __builtin_nontemporal_store(h[j], &dst[j]);
}

// C: collapse NSLICE slices per (half, word), unpack u16 pairs -> cnt + count
__global__ __launch_bounds__(256) void reduce_kernel(
    const unsigned int* __restrict__ parts, int* __restrict__ cnt,
    float* __restrict__ out_count)
{
    int j = blockIdx.x * 256 + threadIdx.x;  // word index in [0, HWORDS)
    if (j >= HWORDS) return;
#pragma unroll
    for (int half = 0; half < 2; ++half) {
        unsigned int sum = 0;
        for (int s = 0; s < NSLICE; ++s)
            sum += parts[(long long)(2 * s + half) * HWORDS + j];
        int b = half * HALF + 2 * j;
        int c0 = (int)(sum & 0xFFFFu), c1 = (int)(sum >> 16);
        cnt[b]     = c0;
        cnt[b + 1] = c1;
        out_count[b]     = (float)c0;
        out_count[b + 1] = (float)c1;
    }
}

// D: parallel scan — 54 blocks; each sums everything before its range
__global__ __launch_bounds__(1024) void scan_kernel(
    const int* __restrict__ cnt, float* __restrict__ out_cum)
{
    __shared__ int lds[1024];
    const int t = threadIdx.x;
    const int base = blockIdx.x * 1024;

    int pre = 0;
    for (int j = t; j < base; j += 1024) pre += cnt[j];
    lds[t] = pre;
    __syncthreads();
    for (int off = 512; off > 0; off >>= 1) {
        if (t < off) lds[t] += lds[t + off];
        __syncthreads();
    }
    const int blockpre = lds[0];
    __syncthreads();

    const int idx = base + t;
    const int c = (idx < TOTAL) ? cnt[idx] : 0;

    lds[t] = c;
    __syncthreads();
    for (int off = 1; off < 1024; off <<= 1) {
        int vprev = (t >= off) ? lds[t - off] : 0;
        __syncthreads();
        lds[t] += vprev;
        __syncthreads();
    }
    const int exc = lds[t] - c;

    if (idx < TOTAL)
        __builtin_nontemporal_store((float)(blockpre + exc), &out_cum[idx]);
}

extern "C" void kernel_launch(void* const* d_in, const int* in_sizes, int n_in,
                              void* d_out, int out_size, void* d_ws, size_t ws_size,
                              hipStream_t stream)
{
    const float* coords = (const float*)d_in[0];
    const float* cell   = (const float*)d_in[1];
    float* out = (float*)d_out;
    unsigned int* parts = (unsigned int*)d_ws;           // 128*HWORDS u32 = 7 MB
    int* cnt = (int*)(parts + 2LL * NSLICE * HWORDS);

    // out_size = 30N + 2*TOTAL
    int N = (int)((out_size - 2 * TOTAL) / 30);

    cell_atoms_kernel<<<(N + BS - 1) / BS, BS, 0, stream>>>(coords, cell, out, N);

    long long off4 = 30LL * N;  // count then cumcount at the tail
    hist_kernel<<<2 * NSLICE, 1024, 0, stream>>>(out + 3LL * N, parts, N);
    reduce_kernel<<<(HWORDS + 255) / 256, 256, 0, stream>>>(parts, cnt, out + off4);
    scan_kernel<<<(TOTAL + 1023) / 1024, 1024, 0, stream>>>(cnt, out + off4 + TOTAL);
}